// Round 2
// baseline (9691.668 us; speedup 1.0000x reference)
//
#include <hip/hip_runtime.h>
#include <math.h>

#define C       128
#define KCODES  1024
#define TPB     256
#define KSPLIT  4
#define KPART   (KCODES / KSPLIT)   // 256 codes per partition
#define TILE    32                  // codes per LDS tile (16 KB)
#define NTILES  (KPART / TILE)      // 8
#define EPS     0.125f

// ---------------- pass 0: ||c||^2 for all codes -> ws ----------------
__global__ void cbsq_kernel(const float* __restrict__ cb, float* __restrict__ cbsq) {
    const int k = blockIdx.x * blockDim.x + threadIdx.x;
    if (k >= KCODES) return;
    const float4* cp = (const float4*)(cb + (size_t)k * C);
    float sx = 0.f, sy = 0.f, sz = 0.f, sw = 0.f;
    #pragma unroll
    for (int i = 0; i < C / 4; ++i) {
        float4 v = cp[i];
        sx += v.x * v.x; sy += v.y * v.y;
        sz += v.z * v.z; sw += v.w * v.w;
    }
    cbsq[k] = (sx + sy) + (sz + sw);   // same combine order as R1
}

// ---------------- pass 1: per-(row, K-partition) top-2 ----------------
// One thread per row; each block handles 256 rows x 256 codes via 8 LDS tiles
// of 32 codes. Row stays in VGPRs; tile reads are wave-uniform (broadcast,
// conflict-free ds_read_b128). 4 parallel accumulator chains (one per code),
// each chain sequential over c (bit-identical to the R1 arithmetic order).
__global__ __launch_bounds__(TPB, 3)
void vq_partial_kernel(const float* __restrict__ x,
                       const float* __restrict__ cb,
                       const float* __restrict__ cbsq,
                       float4* __restrict__ partials,   // [rows][KSPLIT]
                       int rows)
{
    __shared__ float s_tile[TILE * C];   // 16 KB
    __shared__ float s_cbsq[KPART];      // 1 KB
    const int t     = threadIdx.x;
    const int rb    = blockIdx.x;
    const int ks    = blockIdx.y;
    const int kbase = ks * KPART;

    s_cbsq[t] = cbsq[kbase + t];         // TPB == KPART == 256

    const int row_raw = rb * TPB + t;
    const bool valid  = row_raw < rows;
    const int row     = valid ? row_raw : (rows - 1);

    // row -> registers (each lane reads its own 512B stretch; lines fully consumed)
    float4 xr4[C / 4];
    {
        const float4* xp = (const float4*)(x + (size_t)row * C);
        #pragma unroll
        for (int i = 0; i < C / 4; ++i) xr4[i] = xp[i];
    }
    float rs;
    {
        float sx = 0.f, sy = 0.f, sz = 0.f, sw = 0.f;
        #pragma unroll
        for (int i = 0; i < C / 4; ++i) {
            sx += xr4[i].x * xr4[i].x; sy += xr4[i].y * xr4[i].y;
            sz += xr4[i].z * xr4[i].z; sw += xr4[i].w * xr4[i].w;
        }
        rs = (sx + sy) + (sz + sw);      // same combine order as R1
    }

    float v1 = INFINITY, v2 = INFINITY;
    int   k1 = 0,        k2 = 0;

    #pragma unroll 1
    for (int tile = 0; tile < NTILES; ++tile) {
        __syncthreads();                 // previous tile fully consumed
        // stage 32 codes (1024 float4); 256 threads x 4 float4, coalesced
        {
            const float4* gsrc = (const float4*)(cb + (size_t)(kbase + tile * TILE) * C);
            float4* ldst = (float4*)s_tile;
            #pragma unroll
            for (int j = 0; j < 4; ++j) ldst[j * TPB + t] = gsrc[j * TPB + t];
        }
        __syncthreads();

        #pragma unroll 1
        for (int kt = 0; kt < TILE; kt += 4) {
            const float4* c0 = (const float4*)(s_tile + (size_t)kt * C);
            float a0 = 0.f, a1 = 0.f, a2 = 0.f, a3 = 0.f;
            #pragma unroll
            for (int i = 0; i < C / 4; ++i) {
                const float4 xc = xr4[i];
                const float4 b0 = c0[i];
                const float4 b1 = c0[32 + i];
                const float4 b2 = c0[64 + i];
                const float4 b3 = c0[96 + i];
                a0 = fmaf(xc.x, b0.x, a0); a0 = fmaf(xc.y, b0.y, a0);
                a0 = fmaf(xc.z, b0.z, a0); a0 = fmaf(xc.w, b0.w, a0);
                a1 = fmaf(xc.x, b1.x, a1); a1 = fmaf(xc.y, b1.y, a1);
                a1 = fmaf(xc.z, b1.z, a1); a1 = fmaf(xc.w, b1.w, a1);
                a2 = fmaf(xc.x, b2.x, a2); a2 = fmaf(xc.y, b2.y, a2);
                a2 = fmaf(xc.z, b2.z, a2); a2 = fmaf(xc.w, b2.w, a2);
                a3 = fmaf(xc.x, b3.x, a3); a3 = fmaf(xc.y, b3.y, a3);
                a3 = fmaf(xc.z, b3.z, a3); a3 = fmaf(xc.w, b3.w, a3);
            }
            const int klocal = tile * TILE + kt;
            const int kg     = kbase + klocal;
            const float d0 = (rs + s_cbsq[klocal + 0]) - 2.f * a0;
            const float d1 = (rs + s_cbsq[klocal + 1]) - 2.f * a1;
            const float d2 = (rs + s_cbsq[klocal + 2]) - 2.f * a2;
            const float d3 = (rs + s_cbsq[klocal + 3]) - 2.f * a3;
            #define UPD(dv, ki)                                                 \
                if ((dv) < v1)      { v2 = v1; k2 = k1; v1 = (dv); k1 = (ki); } \
                else if ((dv) < v2) { v2 = (dv); k2 = (ki); }
            UPD(d0, kg + 0); UPD(d1, kg + 1); UPD(d2, kg + 2); UPD(d3, kg + 3);
            #undef UPD
        }
    }

    if (valid)
        partials[(size_t)row_raw * KSPLIT + ks] =
            make_float4(v1, v2, __int_as_float(k1), __int_as_float(k2));
}

// ---------------- pass 2: merge partitions, fp64 re-decide, gather ----------------
__global__ __launch_bounds__(TPB, 1)
void vq_final_kernel(const float* __restrict__ x,
                     const float* __restrict__ cb,
                     const float4* __restrict__ partials,
                     float* __restrict__ out_codes,
                     float* __restrict__ out_fidx,
                     float* __restrict__ out_idx,
                     float* __restrict__ out_dist,
                     int rows)
{
    const int row = blockIdx.x * TPB + threadIdx.x;
    if (row >= rows) return;

    float v1 = INFINITY, v2 = INFINITY;
    int   k1 = 0x7fffffff, k2 = 0x7fffffff;
    #pragma unroll
    for (int p = 0; p < KSPLIT; ++p) {
        const float4 pt = partials[(size_t)row * KSPLIT + p];
        const float pv1 = pt.x, pv2 = pt.y;
        const int   pk1 = __float_as_int(pt.z), pk2 = __float_as_int(pt.w);
        // lexicographic (v, k) top-2 == global first-occurrence argmin
        if (pv1 < v1 || (pv1 == v1 && pk1 < k1)) { v2 = v1; k2 = k1; v1 = pv1; k1 = pk1; }
        else if (pv1 < v2 || (pv1 == v2 && pk1 < k2)) { v2 = pv1; k2 = pk1; }
        if (pv2 < v1 || (pv2 == v1 && pk2 < k1)) { v2 = v1; k2 = k1; v1 = pv2; k1 = pk2; }
        else if (pv2 < v2 || (pv2 == v2 && pk2 < k2)) { v2 = pv2; k2 = pk2; }
    }

    // fp64 re-decide for near-ties (identical formula to R1)
    if (v2 - v1 < EPS) {
        const float* xrp = x  + (size_t)row * C;
        const float* c1p = cb + (size_t)k1 * C;
        const float* c2p = cb + (size_t)k2 * C;
        double dot1 = 0.0, cq1 = 0.0, dot2 = 0.0, cq2 = 0.0;
        #pragma unroll 8
        for (int c = 0; c < C; ++c) {
            const double xc  = (double)xrp[c];
            const double cv1 = (double)c1p[c];
            const double cv2 = (double)c2p[c];
            dot1 += xc * cv1;  cq1 += cv1 * cv1;
            dot2 += xc * cv2;  cq2 += cv2 * cv2;
        }
        const double q1 = cq1 - 2.0 * dot1;
        const double q2 = cq2 - 2.0 * dot2;
        if (q2 < q1 || (q2 == q1 && k2 < k1)) {
            k1 = k2;
            // rs in the R1 fp32 order
            float sx = 0.f, sy = 0.f, sz = 0.f, sw = 0.f;
            const float4* xp = (const float4*)xrp;
            #pragma unroll
            for (int i = 0; i < C / 4; ++i) {
                float4 v = xp[i];
                sx += v.x * v.x; sy += v.y * v.y;
                sz += v.z * v.z; sw += v.w * v.w;
            }
            const float rs = (sx + sy) + (sz + sw);
            v1 = (float)((double)rs + q2);
        }
    }

    // outputs
    {
        const float4* src = (const float4*)(cb + (size_t)k1 * C);
        float4*       dst = (float4*)(out_codes + (size_t)row * C);
        #pragma unroll
        for (int i = 0; i < C / 4; ++i) dst[i] = src[i];
        out_fidx[row] = (float)k1;
        out_idx[row]  = (float)k1;
        out_dist[row] = v1;
    }
}

// ---------------- fallback (R1 kernel, no workspace needed) ----------------
__global__ __launch_bounds__(TPB, 1)
void vq_nearest_fallback(const float* __restrict__ x,
                         const float* __restrict__ cb,
                         float* __restrict__ out_codes,
                         float* __restrict__ out_fidx,
                         float* __restrict__ out_idx,
                         float* __restrict__ out_dist,
                         int rows)
{
    __shared__ float s_cbsq[KCODES];
    const int t = threadIdx.x;
    for (int k = t; k < KCODES; k += TPB) {
        const float4* cp = (const float4*)(cb + (size_t)k * C);
        float sx = 0.f, sy = 0.f, sz = 0.f, sw = 0.f;
        #pragma unroll
        for (int i = 0; i < C / 4; ++i) {
            float4 v = cp[i];
            sx += v.x * v.x; sy += v.y * v.y; sz += v.z * v.z; sw += v.w * v.w;
        }
        s_cbsq[k] = (sx + sy) + (sz + sw);
    }
    __syncthreads();
    const int row = blockIdx.x * TPB + t;
    if (row >= rows) return;
    float xr[C];
    {
        const float4* xp = (const float4*)(x + (size_t)row * C);
        #pragma unroll
        for (int i = 0; i < C / 4; ++i) {
            float4 v = xp[i];
            xr[4*i+0] = v.x; xr[4*i+1] = v.y; xr[4*i+2] = v.z; xr[4*i+3] = v.w;
        }
    }
    float rs;
    {
        float sx = 0.f, sy = 0.f, sz = 0.f, sw = 0.f;
        #pragma unroll
        for (int i = 0; i < C / 4; ++i) {
            sx += xr[4*i+0]*xr[4*i+0]; sy += xr[4*i+1]*xr[4*i+1];
            sz += xr[4*i+2]*xr[4*i+2]; sw += xr[4*i+3]*xr[4*i+3];
        }
        rs = (sx + sy) + (sz + sw);
    }
    float v1 = INFINITY, v2 = INFINITY; int k1 = 0, k2 = 0;
    #pragma unroll 1
    for (int k0 = 0; k0 < KCODES; k0 += 4) {
        const float* c0 = cb + (size_t)k0 * C;
        float a0 = 0.f, a1 = 0.f, a2 = 0.f, a3 = 0.f;
        #pragma unroll
        for (int c = 0; c < C; ++c) {
            const float xc = xr[c];
            a0 = fmaf(xc, c0[c], a0);
            a1 = fmaf(xc, c0[C + c], a1);
            a2 = fmaf(xc, c0[2*C + c], a2);
            a3 = fmaf(xc, c0[3*C + c], a3);
        }
        const float d0 = (rs + s_cbsq[k0+0]) - 2.f * a0;
        const float d1 = (rs + s_cbsq[k0+1]) - 2.f * a1;
        const float d2 = (rs + s_cbsq[k0+2]) - 2.f * a2;
        const float d3 = (rs + s_cbsq[k0+3]) - 2.f * a3;
        #define UPD(dv, ki)                                                 \
            if ((dv) < v1)      { v2 = v1; k2 = k1; v1 = (dv); k1 = (ki); } \
            else if ((dv) < v2) { v2 = (dv); k2 = (ki); }
        UPD(d0, k0+0); UPD(d1, k0+1); UPD(d2, k0+2); UPD(d3, k0+3);
        #undef UPD
    }
    if (v2 - v1 < EPS) {
        const float* c1p = cb + (size_t)k1 * C;
        const float* c2p = cb + (size_t)k2 * C;
        double dot1 = 0.0, cq1 = 0.0, dot2 = 0.0, cq2 = 0.0;
        #pragma unroll 8
        for (int c = 0; c < C; ++c) {
            const double xc = (double)xr[c];
            const double cv1 = (double)c1p[c];
            const double cv2 = (double)c2p[c];
            dot1 += xc * cv1; cq1 += cv1 * cv1;
            dot2 += xc * cv2; cq2 += cv2 * cv2;
        }
        const double q1 = cq1 - 2.0 * dot1;
        const double q2 = cq2 - 2.0 * dot2;
        if (q2 < q1 || (q2 == q1 && k2 < k1)) { k1 = k2; v1 = (float)((double)rs + q2); }
    }
    {
        const float4* src = (const float4*)(cb + (size_t)k1 * C);
        float4* dst = (float4*)(out_codes + (size_t)row * C);
        #pragma unroll
        for (int i = 0; i < C / 4; ++i) dst[i] = src[i];
        out_fidx[row] = (float)k1;
        out_idx[row]  = (float)k1;
        out_dist[row] = v1;
    }
}

extern "C" void kernel_launch(void* const* d_in, const int* in_sizes, int n_in,
                              void* d_out, int out_size, void* d_ws, size_t ws_size,
                              hipStream_t stream) {
    const float* x  = (const float*)d_in[0];
    const float* cb = (const float*)d_in[1];
    const int rows = in_sizes[0] / C;   // 65536

    float* out       = (float*)d_out;
    float* out_codes = out;                          // rows*C
    float* out_fidx  = out + (size_t)rows * C;       // rows
    float* out_idx   = out_fidx + rows;              // rows
    float* out_dist  = out_idx + rows;               // rows

    const int rowblocks = (rows + TPB - 1) / TPB;    // 256

    const size_t partial_bytes = (size_t)rows * KSPLIT * sizeof(float4); // 4 MB
    const size_t need = partial_bytes + (size_t)KCODES * sizeof(float);

    if (ws_size >= need) {
        float4* partials = (float4*)d_ws;
        float*  cbsq     = (float*)((char*)d_ws + partial_bytes);
        cbsq_kernel<<<(KCODES + TPB - 1) / TPB, TPB, 0, stream>>>(cb, cbsq);
        dim3 grid1(rowblocks, KSPLIT);
        vq_partial_kernel<<<grid1, TPB, 0, stream>>>(x, cb, cbsq, partials, rows);
        vq_final_kernel<<<rowblocks, TPB, 0, stream>>>(x, cb, partials,
                                                       out_codes, out_fidx,
                                                       out_idx, out_dist, rows);
    } else {
        vq_nearest_fallback<<<rowblocks, TPB, 0, stream>>>(x, cb, out_codes, out_fidx,
                                                           out_idx, out_dist, rows);
    }
}

// Round 3
// 173.727 us; speedup vs baseline: 55.7869x; 55.7869x over previous
//
#include <hip/hip_runtime.h>
#include <math.h>
#include <stdint.h>

#define C        128
#define KCODES   1024
#define TPB      256
#define ROWS_PB  128                  // rows per block
#define NCHUNK   64                   // codes per LDS chunk
#define NCHUNKS  (KCODES / NCHUNK)    // 16
#define BSTRIDE  272                  // padded row stride (bytes) = 128*2 + 16
#define EPS_TRIG 0.25f

typedef __attribute__((ext_vector_type(8))) short bf16x8_t;
typedef __attribute__((ext_vector_type(4))) float f32x4_t;

static __device__ __forceinline__ uint32_t bf16_rne(float f) {
    uint32_t u = __float_as_uint(f);
    return (u + 0x7FFFu + ((u >> 16) & 1u)) >> 16;
}
static __device__ __forceinline__ float bf16_hi_f(float f) {
    return __uint_as_float(bf16_rne(f) << 16);
}

// ---------------- prep: split codebook into bf16 hi/lo ----------------
__global__ void cb_split_kernel(const float* __restrict__ cb,
                                uint16_t* __restrict__ cbh,
                                uint16_t* __restrict__ cbl) {
    int i = blockIdx.x * blockDim.x + threadIdx.x;
    if (i >= KCODES * C) return;
    float f = cb[i];
    uint32_t h = bf16_rne(f);
    float lo = f - __uint_as_float(h << 16);
    cbh[i] = (uint16_t)h;
    cbl[i] = (uint16_t)bf16_rne(lo);
}

// ---------------- prep: ||c||^2 (R1 arithmetic order) ----------------
__global__ void cbsq_kernel(const float* __restrict__ cb, float* __restrict__ cbsq) {
    const int k = blockIdx.x * blockDim.x + threadIdx.x;
    if (k >= KCODES) return;
    const float4* cp = (const float4*)(cb + (size_t)k * C);
    float sx = 0.f, sy = 0.f, sz = 0.f, sw = 0.f;
    #pragma unroll
    for (int i = 0; i < C / 4; ++i) {
        float4 v = cp[i];
        sx += v.x * v.x; sy += v.y * v.y;
        sz += v.z * v.z; sw += v.w * v.w;
    }
    cbsq[k] = (sx + sy) + (sz + sw);
}

// ---------------- main: MFMA distance + in-block argmin ----------------
#define SLOTS(OP) OP(0,0) OP(0,1) OP(0,2) OP(0,3) OP(1,0) OP(1,1) OP(1,2) OP(1,3)
#define MFMA_BF16 __builtin_amdgcn_mfma_f32_16x16x32_bf16

__global__ __launch_bounds__(TPB, 3)
void vq_mfma_kernel(const float* __restrict__ x,
                    const float* __restrict__ cb,
                    const uint16_t* __restrict__ cbh,
                    const uint16_t* __restrict__ cbl,
                    const float* __restrict__ cq,
                    float* __restrict__ out_codes,
                    float* __restrict__ out_fidx,
                    float* __restrict__ out_idx,
                    float* __restrict__ out_dist,
                    int rows)
{
    __shared__ __align__(16) uint8_t s_buf[NCHUNK * 2 * BSTRIDE];  // 34816 B, also A-stage area
    __shared__ float s_cq[NCHUNK];
    __shared__ float s_v1[ROWS_PB], s_v2[ROWS_PB];
    __shared__ int   s_k1[ROWS_PB], s_k2[ROWS_PB];

    const int t    = threadIdx.x;
    const int lane = t & 63;
    const int w    = t >> 6;       // wave 0..3
    const int ln   = lane & 15;
    const int quad = lane >> 4;
    const int rowblock = blockIdx.x * ROWS_PB;

    // ---- stage x tile -> bf16 HI in s_buf (padded row-major) ----
    #pragma unroll 4
    for (int i = 0; i < 16; ++i) {
        int fid = t + i * TPB;            // float4 id in tile (4096)
        int row = fid >> 5;               // 0..127
        int kq  = fid & 31;               // float4 within row
        int grow = rowblock + row;
        grow = grow < rows ? grow : rows - 1;
        float4 v = ((const float4*)x)[(size_t)grow * 32 + kq];
        uint32_t p0 = bf16_rne(v.x) | (bf16_rne(v.y) << 16);
        uint32_t p1 = bf16_rne(v.z) | (bf16_rne(v.w) << 16);
        *(uint2*)(s_buf + row * BSTRIDE + kq * 8) = make_uint2(p0, p1);
    }
    __syncthreads();

    // ---- A-hi fragments -> registers (live for the whole kernel) ----
    const int arow0 = (w * 32 + ln) * BSTRIDE;        // rowgroup 0
    const int arow1 = (w * 32 + 16 + ln) * BSTRIDE;   // rowgroup 1
    bf16x8_t ah00, ah01, ah02, ah03, ah10, ah11, ah12, ah13;
    ah00 = *(const bf16x8_t*)(s_buf + arow0 + 0 * 64 + quad * 16);
    ah01 = *(const bf16x8_t*)(s_buf + arow0 + 1 * 64 + quad * 16);
    ah02 = *(const bf16x8_t*)(s_buf + arow0 + 2 * 64 + quad * 16);
    ah03 = *(const bf16x8_t*)(s_buf + arow0 + 3 * 64 + quad * 16);
    ah10 = *(const bf16x8_t*)(s_buf + arow1 + 0 * 64 + quad * 16);
    ah11 = *(const bf16x8_t*)(s_buf + arow1 + 1 * 64 + quad * 16);
    ah12 = *(const bf16x8_t*)(s_buf + arow1 + 2 * 64 + quad * 16);
    ah13 = *(const bf16x8_t*)(s_buf + arow1 + 3 * 64 + quad * 16);
    __syncthreads();

    // ---- stage x tile -> bf16 LO ----
    #pragma unroll 4
    for (int i = 0; i < 16; ++i) {
        int fid = t + i * TPB;
        int row = fid >> 5;
        int kq  = fid & 31;
        int grow = rowblock + row;
        grow = grow < rows ? grow : rows - 1;
        float4 v = ((const float4*)x)[(size_t)grow * 32 + kq];
        uint32_t p0 = bf16_rne(v.x - bf16_hi_f(v.x)) | (bf16_rne(v.y - bf16_hi_f(v.y)) << 16);
        uint32_t p1 = bf16_rne(v.z - bf16_hi_f(v.z)) | (bf16_rne(v.w - bf16_hi_f(v.w)) << 16);
        *(uint2*)(s_buf + row * BSTRIDE + kq * 8) = make_uint2(p0, p1);
    }
    __syncthreads();

    bf16x8_t al00, al01, al02, al03, al10, al11, al12, al13;
    al00 = *(const bf16x8_t*)(s_buf + arow0 + 0 * 64 + quad * 16);
    al01 = *(const bf16x8_t*)(s_buf + arow0 + 1 * 64 + quad * 16);
    al02 = *(const bf16x8_t*)(s_buf + arow0 + 2 * 64 + quad * 16);
    al03 = *(const bf16x8_t*)(s_buf + arow0 + 3 * 64 + quad * 16);
    al10 = *(const bf16x8_t*)(s_buf + arow1 + 0 * 64 + quad * 16);
    al11 = *(const bf16x8_t*)(s_buf + arow1 + 1 * 64 + quad * 16);
    al12 = *(const bf16x8_t*)(s_buf + arow1 + 2 * 64 + quad * 16);
    al13 = *(const bf16x8_t*)(s_buf + arow1 + 3 * 64 + quad * 16);
    __syncthreads();

    // ---- per-lane top-2 state (8 row-slots) ----
#define DECL(g,r) float v1_##g##r = INFINITY, v2_##g##r = INFINITY; int k1_##g##r = 0, k2_##g##r = 0;
    SLOTS(DECL)
#undef DECL

    #pragma unroll 1
    for (int chn = 0; chn < NCHUNKS; ++chn) {
        const int kbase = chn * NCHUNK;
        // stage B chunk: 64 codes hi + lo (padded rows)
        #pragma unroll
        for (int i = 0; i < 4; ++i) {
            int uid  = t + i * TPB;          // uint4 id (1024)
            int code = uid >> 4, g = uid & 15;
            uint4 dh = ((const uint4*)cbh)[(size_t)(kbase + code) * 16 + g];
            *(uint4*)(s_buf + code * BSTRIDE + g * 16) = dh;
            uint4 dl = ((const uint4*)cbl)[(size_t)(kbase + code) * 16 + g];
            *(uint4*)(s_buf + NCHUNK * BSTRIDE + code * BSTRIDE + g * 16) = dl;
        }
        if (t < NCHUNK) s_cq[t] = cq[kbase + t];
        __syncthreads();

        const uint8_t* bbase  = s_buf + (size_t)ln * BSTRIDE + quad * 16;  // +ct*16*BSTRIDE per tile
        #pragma unroll
        for (int ct = 0; ct < 4; ++ct) {
            const uint8_t* bh_p = bbase + (size_t)ct * 16 * BSTRIDE;
            const uint8_t* bl_p = bh_p + NCHUNK * BSTRIDE;
            f32x4_t acc0 = {0.f, 0.f, 0.f, 0.f};
            f32x4_t acc1 = {0.f, 0.f, 0.f, 0.f};
#define KSTEP(kk) { \
            bf16x8_t bh = *(const bf16x8_t*)(bh_p + kk * 64); \
            bf16x8_t bl = *(const bf16x8_t*)(bl_p + kk * 64); \
            acc0 = MFMA_BF16(ah0##kk, bh, acc0, 0, 0, 0); \
            acc0 = MFMA_BF16(al0##kk, bh, acc0, 0, 0, 0); \
            acc0 = MFMA_BF16(ah0##kk, bl, acc0, 0, 0, 0); \
            acc1 = MFMA_BF16(ah1##kk, bh, acc1, 0, 0, 0); \
            acc1 = MFMA_BF16(al1##kk, bh, acc1, 0, 0, 0); \
            acc1 = MFMA_BF16(ah1##kk, bl, acc1, 0, 0, 0); }
            KSTEP(0) KSTEP(1) KSTEP(2) KSTEP(3)
#undef KSTEP
            const float cqv = s_cq[ct * 16 + ln];
            const int   kc  = kbase + ct * 16 + ln;
#define UPD(g,r) { \
            float s_ = fmaf(-2.0f, (g ? acc1 : acc0)[r], cqv); \
            bool c1_ = s_ < v1_##g##r; \
            bool c2_ = s_ < v2_##g##r; \
            v2_##g##r = c1_ ? v1_##g##r : (c2_ ? s_ : v2_##g##r); \
            k2_##g##r = c1_ ? k1_##g##r : (c2_ ? kc : k2_##g##r); \
            v1_##g##r = c1_ ? s_ : v1_##g##r; \
            k1_##g##r = c1_ ? kc : k1_##g##r; }
            SLOTS(UPD)
#undef UPD
        }
        __syncthreads();
    }

    // ---- butterfly merge across the 16 lanes of each col-group ----
    for (int m_ = 1; m_ <= 8; m_ <<= 1) {
#define MRG(g,r) { \
        float ov1 = __shfl_xor(v1_##g##r, m_, 16); int ok1 = __shfl_xor(k1_##g##r, m_, 16); \
        float ov2 = __shfl_xor(v2_##g##r, m_, 16); int ok2 = __shfl_xor(k2_##g##r, m_, 16); \
        if (ov1 < v1_##g##r || (ov1 == v1_##g##r && ok1 < k1_##g##r)) { \
            if (v1_##g##r < ov2 || (v1_##g##r == ov2 && k1_##g##r < ok2)) { v2_##g##r = v1_##g##r; k2_##g##r = k1_##g##r; } \
            else { v2_##g##r = ov2; k2_##g##r = ok2; } \
            v1_##g##r = ov1; k1_##g##r = ok1; \
        } else if (ov1 < v2_##g##r || (ov1 == v2_##g##r && ok1 < k2_##g##r)) { \
            v2_##g##r = ov1; k2_##g##r = ok1; \
        } }
        SLOTS(MRG)
#undef MRG
    }
    if (ln == 0) {
#define WRT(g,r) { int rloc = w * 32 + g * 16 + quad * 4 + r; \
        s_v1[rloc] = v1_##g##r; s_v2[rloc] = v2_##g##r; \
        s_k1[rloc] = k1_##g##r; s_k2[rloc] = k2_##g##r; }
        SLOTS(WRT)
#undef WRT
    }
    __syncthreads();

    // ---- per-row finalize: fp32 R1-order distance + fp64 near-tie re-decide ----
    if (t < ROWS_PB) {
        int rowg = rowblock + t;
        const bool valid = rowg < rows;
        rowg = valid ? rowg : rows - 1;
        float v1 = s_v1[t], v2 = s_v2[t];
        int k1 = s_k1[t], k2 = s_k2[t];
        const float* xr = x + (size_t)rowg * C;

        // rs in R1 float4 order
        float sx = 0.f, sy = 0.f, sz = 0.f, sw = 0.f;
        {
            const float4* xp = (const float4*)xr;
            #pragma unroll
            for (int i = 0; i < C / 4; ++i) {
                float4 v = xp[i];
                sx += v.x * v.x; sy += v.y * v.y;
                sz += v.z * v.z; sw += v.w * v.w;
            }
        }
        const float rs = (sx + sy) + (sz + sw);

        bool switched = false;
        double qwin = 0.0;
        if (v2 - v1 < EPS_TRIG) {
            const float* c1p = cb + (size_t)k1 * C;
            const float* c2p = cb + (size_t)k2 * C;
            double dot1 = 0.0, cq1 = 0.0, dot2 = 0.0, cq2 = 0.0;
            #pragma unroll 8
            for (int c = 0; c < C; ++c) {
                const double xc  = (double)xr[c];
                const double cv1 = (double)c1p[c];
                const double cv2 = (double)c2p[c];
                dot1 += xc * cv1;  cq1 += cv1 * cv1;
                dot2 += xc * cv2;  cq2 += cv2 * cv2;
            }
            const double q1 = cq1 - 2.0 * dot1;
            const double q2 = cq2 - 2.0 * dot2;
            if (q2 < q1 || (q2 == q1 && k2 < k1)) { k1 = k2; switched = true; qwin = q2; }
        }

        // exact fp32 distance for the final k1 (R1 chain order)
        const float* c1p = cb + (size_t)k1 * C;
        float a = 0.f;
        #pragma unroll 16
        for (int c = 0; c < C; ++c) a = fmaf(xr[c], c1p[c], a);
        float d = (rs + cq[k1]) - 2.f * a;
        if (switched) d = (float)((double)rs + qwin);

        if (valid) {
            out_fidx[rowg] = (float)k1;
            out_idx[rowg]  = (float)k1;
            out_dist[rowg] = d;
        }
        s_k1[t] = k1;   // final index for the gather
    }
    __syncthreads();

    // ---- gather codes: 2 threads per row ----
    {
        const int r    = t >> 1;
        const int half = t & 1;
        const int rowg = rowblock + r;
        if (rowg < rows) {
            const int k1 = s_k1[r];
            const float4* src = (const float4*)(cb + (size_t)k1 * C) + half * 16;
            float4*       dst = (float4*)(out_codes + (size_t)rowg * C) + half * 16;
            #pragma unroll
            for (int i = 0; i < 16; ++i) dst[i] = src[i];
        }
    }
}

// ---------------- fallback (R1 kernel, needs no workspace) ----------------
__global__ __launch_bounds__(TPB, 1)
void vq_nearest_fallback(const float* __restrict__ x,
                         const float* __restrict__ cb,
                         float* __restrict__ out_codes,
                         float* __restrict__ out_fidx,
                         float* __restrict__ out_idx,
                         float* __restrict__ out_dist,
                         int rows)
{
    __shared__ float s_cbsq[KCODES];
    const int t = threadIdx.x;
    for (int k = t; k < KCODES; k += TPB) {
        const float4* cp = (const float4*)(cb + (size_t)k * C);
        float sx = 0.f, sy = 0.f, sz = 0.f, sw = 0.f;
        #pragma unroll
        for (int i = 0; i < C / 4; ++i) {
            float4 v = cp[i];
            sx += v.x * v.x; sy += v.y * v.y; sz += v.z * v.z; sw += v.w * v.w;
        }
        s_cbsq[k] = (sx + sy) + (sz + sw);
    }
    __syncthreads();
    const int row = blockIdx.x * TPB + t;
    if (row >= rows) return;
    float xr[C];
    {
        const float4* xp = (const float4*)(x + (size_t)row * C);
        #pragma unroll
        for (int i = 0; i < C / 4; ++i) {
            float4 v = xp[i];
            xr[4*i+0] = v.x; xr[4*i+1] = v.y; xr[4*i+2] = v.z; xr[4*i+3] = v.w;
        }
    }
    float rs;
    {
        float sx = 0.f, sy = 0.f, sz = 0.f, sw = 0.f;
        #pragma unroll
        for (int i = 0; i < C / 4; ++i) {
            sx += xr[4*i+0]*xr[4*i+0]; sy += xr[4*i+1]*xr[4*i+1];
            sz += xr[4*i+2]*xr[4*i+2]; sw += xr[4*i+3]*xr[4*i+3];
        }
        rs = (sx + sy) + (sz + sw);
    }
    float v1 = INFINITY, v2 = INFINITY; int k1 = 0, k2 = 0;
    #pragma unroll 1
    for (int k0 = 0; k0 < KCODES; k0 += 4) {
        const float* c0 = cb + (size_t)k0 * C;
        float a0 = 0.f, a1 = 0.f, a2 = 0.f, a3 = 0.f;
        #pragma unroll
        for (int c = 0; c < C; ++c) {
            const float xc = xr[c];
            a0 = fmaf(xc, c0[c], a0);
            a1 = fmaf(xc, c0[C + c], a1);
            a2 = fmaf(xc, c0[2*C + c], a2);
            a3 = fmaf(xc, c0[3*C + c], a3);
        }
        const float d0 = (rs + s_cbsq[k0+0]) - 2.f * a0;
        const float d1 = (rs + s_cbsq[k0+1]) - 2.f * a1;
        const float d2 = (rs + s_cbsq[k0+2]) - 2.f * a2;
        const float d3 = (rs + s_cbsq[k0+3]) - 2.f * a3;
        #define UPDF(dv, ki)                                                 \
            if ((dv) < v1)      { v2 = v1; k2 = k1; v1 = (dv); k1 = (ki); } \
            else if ((dv) < v2) { v2 = (dv); k2 = (ki); }
        UPDF(d0, k0+0); UPDF(d1, k0+1); UPDF(d2, k0+2); UPDF(d3, k0+3);
        #undef UPDF
    }
    if (v2 - v1 < 0.125f) {
        const float* c1p = cb + (size_t)k1 * C;
        const float* c2p = cb + (size_t)k2 * C;
        double dot1 = 0.0, cq1 = 0.0, dot2 = 0.0, cq2 = 0.0;
        #pragma unroll 8
        for (int c = 0; c < C; ++c) {
            const double xc = (double)xr[c];
            const double cv1 = (double)c1p[c];
            const double cv2 = (double)c2p[c];
            dot1 += xc * cv1; cq1 += cv1 * cv1;
            dot2 += xc * cv2; cq2 += cv2 * cv2;
        }
        const double q1 = cq1 - 2.0 * dot1;
        const double q2 = cq2 - 2.0 * dot2;
        if (q2 < q1 || (q2 == q1 && k2 < k1)) { k1 = k2; v1 = (float)((double)rs + q2); }
    }
    {
        const float4* src = (const float4*)(cb + (size_t)k1 * C);
        float4* dst = (float4*)(out_codes + (size_t)row * C);
        #pragma unroll
        for (int i = 0; i < C / 4; ++i) dst[i] = src[i];
        out_fidx[row] = (float)k1;
        out_idx[row]  = (float)k1;
        out_dist[row] = v1;
    }
}

extern "C" void kernel_launch(void* const* d_in, const int* in_sizes, int n_in,
                              void* d_out, int out_size, void* d_ws, size_t ws_size,
                              hipStream_t stream) {
    const float* x  = (const float*)d_in[0];
    const float* cb = (const float*)d_in[1];
    const int rows = in_sizes[0] / C;   // 65536

    float* out       = (float*)d_out;
    float* out_codes = out;                          // rows*C
    float* out_fidx  = out + (size_t)rows * C;       // rows
    float* out_idx   = out_fidx + rows;              // rows
    float* out_dist  = out_idx + rows;               // rows

    // workspace layout
    const size_t cbh_off = 0;
    const size_t cbl_off = (size_t)KCODES * C * sizeof(uint16_t);      // 256 KB
    const size_t cq_off  = cbl_off * 2;                                // 512 KB
    const size_t need    = cq_off + KCODES * sizeof(float);

    if (ws_size >= need) {
        uint16_t* cbh = (uint16_t*)((char*)d_ws + cbh_off);
        uint16_t* cbl = (uint16_t*)((char*)d_ws + cbl_off);
        float*    cq  = (float*)((char*)d_ws + cq_off);

        cb_split_kernel<<<(KCODES * C + TPB - 1) / TPB, TPB, 0, stream>>>(cb, cbh, cbl);
        cbsq_kernel<<<(KCODES + TPB - 1) / TPB, TPB, 0, stream>>>(cb, cq);

        const int grid = (rows + ROWS_PB - 1) / ROWS_PB;   // 512
        vq_mfma_kernel<<<grid, TPB, 0, stream>>>(x, cb, cbh, cbl, cq,
                                                 out_codes, out_fidx, out_idx,
                                                 out_dist, rows);
    } else {
        const int rowblocks = (rows + TPB - 1) / TPB;
        vq_nearest_fallback<<<rowblocks, TPB, 0, stream>>>(x, cb, out_codes, out_fidx,
                                                           out_idx, out_dist, rows);
    }
}